// Round 1
// baseline (228.227 us; speedup 1.0000x reference)
//
#include <hip/hip_runtime.h>
#include <hip/hip_bf16.h>

// Problem constants
#define N_ 64
#define C_ 64
#define T_ 300
#define V_ 25
#define K_ 3
#define TB 4              // t-values per block
#define COLS 100          // TB*V_
#define NFRAG 7           // col fragments (pad 100 -> 112)
#define KC 192            // K_*C_ (stage-B inner dim)
#define ZP 200            // zT pitch in bf16 (192 kc + pad; 400B rows, 16B aligned, bank spread)
#define XP 40             // xs pitch in bf16 (25 v + pad to 40; 80B rows)
#define NBLK 4800         // N_ * T_/TB
#define EPS_ 1e-5f

typedef __bf16 bf16_t;
typedef __bf16 bf16x8 __attribute__((ext_vector_type(8)));
typedef float f32x4 __attribute__((ext_vector_type(4)));

static __device__ __forceinline__ bf16_t tobf(float f) { return (bf16_t)f; }

// ---------------------------------------------------------------------------
// K1: y[n,o,t,w] = sum_k sum_c W[k,o,c] * (sum_v x[n,c,t,v] A[k,v,w]) + bsum[o]
// Both contractions via MFMA 16x16x32 bf16. One block = (n, 4 t-values).
// Writes y (fp32) to global (d_out used as staging) + per-block channel partials.
// ---------------------------------------------------------------------------
__global__ __launch_bounds__(256) void k1_compute(
    const float* __restrict__ x, const float* __restrict__ A,
    const float* __restrict__ W, const float* __restrict__ b,
    float* __restrict__ y, float* __restrict__ pSum, float* __restrict__ pSqs) {
  // LDS: xs 20.5KB + zT 44.8KB + stats 0.5KB = ~65.8KB -> 2 blocks/CU
  __shared__ __align__(16) bf16_t xs[256 * XP];    // row = c*4+tt, col = v (25..31 zeroed)
  __shared__ __align__(16) bf16_t zT[112 * ZP];    // row = local col (tt*25+w), col = kc
  __shared__ float stats[2][64];

  const int bid = blockIdx.x;
  const int n = bid / (T_ / TB);
  const int t0 = (bid % (T_ / TB)) * TB;
  const int tid = threadIdx.x;
  const int lane = tid & 63;
  const int wv = tid >> 6;        // wave 0..3
  const int l15 = lane & 15;
  const int lg = lane >> 4;       // 0..3

  // --- W fragments (stage-B A-operand). Wave wv owns output rows o = wv*16..+15.
  // k-slot convention (same for ALL A/B frags): k = kf*32 + lg*8 + j
  bf16x8 wfrag[6];
  {
    const int o = wv * 16 + l15;
    #pragma unroll
    for (int kf = 0; kf < 6; ++kf) {
      int kc0 = kf * 32 + lg * 8;           // kc = k*64 + c
      int k = kc0 >> 6, c = kc0 & 63;       // 8 consecutive c, same k
      const float* wp = W + ((k * 64 + o) * 64 + c);
      bf16x8 f;
      #pragma unroll
      for (int j = 0; j < 8; ++j) f[j] = tobf(wp[j]);
      wfrag[kf] = f;
    }
  }
  // --- A-matrix fragments (stage-A B-operand): Ak[v][w], v padded 25->32, w padded 25->32
  bf16x8 afrag[3][2];
  #pragma unroll
  for (int k = 0; k < 3; ++k)
    #pragma unroll
    for (int nf = 0; nf < 2; ++nf) {
      int w = nf * 16 + l15;
      bf16x8 f;
      #pragma unroll
      for (int j = 0; j < 8; ++j) {
        int v = lg * 8 + j;
        float val = (v < V_ && w < V_) ? A[(k * V_ + v) * V_ + w] : 0.f;
        f[j] = tobf(val);
      }
      afrag[k][nf] = f;
    }

  // --- load x tile -> xs (bf16). Per c: 100 contiguous floats (4 t-rows).
  {
    // zero the v-pad (v = 25..31 is read by stage-A MFMA)
    #pragma unroll
    for (int v = 25; v < 32; ++v) xs[tid * XP + v] = tobf(0.f);
    const float* xb = x + (size_t)n * 480000 + t0 * 25;
    for (int f4 = tid; f4 < 1600; f4 += 256) {
      int c = f4 / 25, q = f4 % 25;
      const float4 val = *reinterpret_cast<const float4*>(xb + c * 7500 + 4 * q);
      const float* vp = reinterpret_cast<const float*>(&val);
      #pragma unroll
      for (int i = 0; i < 4; ++i) {
        int e = 4 * q + i;                  // 0..99
        int tt = e / 25, v = e % 25;
        xs[(c * 4 + tt) * XP + v] = tobf(vp[i]);
      }
    }
    // zero zT pad rows (cols 100..111, read by stage-B nf=6)
    for (int i = tid; i < 12 * ZP / 2; i += 256)
      reinterpret_cast<unsigned int*>(zT + 100 * ZP)[i] = 0u;
  }
  __syncthreads();

  // --- stage A: z[k*64+c][tt*25+w] = sum_v x[c,tt,v] * A[k,v,w]
  // X rows = c*4+tt (M=256, 16 frags), k-dim = v (one K=32 step). Wave wv does mf = wv*4+i.
  #pragma unroll
  for (int i = 0; i < 4; ++i) {
    int mf = wv * 4 + i;
    int row = mf * 16 + l15;
    bf16x8 xf = *reinterpret_cast<const bf16x8*>(xs + row * XP + lg * 8);
    #pragma unroll
    for (int k = 0; k < 3; ++k)
      #pragma unroll
      for (int nf = 0; nf < 2; ++nf) {
        f32x4 zero = {0.f, 0.f, 0.f, 0.f};
        f32x4 d = __builtin_amdgcn_mfma_f32_16x16x32_bf16(xf, afrag[k][nf], zero, 0, 0, 0);
        // D element (reg r): global row = mf*16 + lg*4 + r  =>  c = mf*4+lg, tt = r
        int w = nf * 16 + l15;
        if (w < V_) {
          int kc = k * 64 + (mf * 4 + lg);
          #pragma unroll
          for (int r = 0; r < 4; ++r)
            zT[(r * 25 + w) * ZP + kc] = tobf(d[r]);
        }
      }
  }
  __syncthreads();

  // --- stage B: Y[o][col] = sum_kc Wcat[o][kc] * z[kc][col]; wave wv -> rows o=wv*16..+15
  f32x4 acc[NFRAG];
  #pragma unroll
  for (int nf = 0; nf < NFRAG; ++nf) { f32x4 z0 = {0.f,0.f,0.f,0.f}; acc[nf] = z0; }
  #pragma unroll
  for (int kf = 0; kf < 6; ++kf) {
    #pragma unroll
    for (int nf = 0; nf < NFRAG; ++nf) {
      bf16x8 zf = *reinterpret_cast<const bf16x8*>(zT + (nf * 16 + l15) * ZP + kf * 32 + lg * 8);
      acc[nf] = __builtin_amdgcn_mfma_f32_16x16x32_bf16(wfrag[kf], zf, acc[nf], 0, 0, 0);
    }
  }

  // --- epilogue: bias, per-channel partial stats, store y
  const int obase = wv * 16 + lg * 4;      // lane's 4 output rows: obase+r
  float bs[4];
  #pragma unroll
  for (int r = 0; r < 4; ++r)
    bs[r] = b[obase + r] + b[64 + obase + r] + b[128 + obase + r];

  float lsum[4] = {0.f,0.f,0.f,0.f}, lsq[4] = {0.f,0.f,0.f,0.f};
  float* yb = y + (size_t)n * 480000 + t0 * 25;
  #pragma unroll
  for (int nf = 0; nf < NFRAG; ++nf) {
    int col = nf * 16 + l15;
    bool ok = col < COLS;
    #pragma unroll
    for (int r = 0; r < 4; ++r) {
      float val = acc[nf][r] + bs[r];
      if (ok) {
        lsum[r] += val;
        lsq[r] += val * val;
        yb[(obase + r) * 7500 + col] = val;
      }
    }
  }
  // reduce across the 16 lanes (l15) that share the same 4 rows
  #pragma unroll
  for (int d = 1; d < 16; d <<= 1) {
    #pragma unroll
    for (int r = 0; r < 4; ++r) {
      lsum[r] += __shfl_xor(lsum[r], d);
      lsq[r]  += __shfl_xor(lsq[r], d);
    }
  }
  if (l15 == 0) {
    #pragma unroll
    for (int r = 0; r < 4; ++r) {
      stats[0][obase + r] = lsum[r];
      stats[1][obase + r] = lsq[r];
    }
  }
  __syncthreads();
  if (tid < 64)        pSum[(size_t)tid * NBLK + bid] = stats[0][tid];
  else if (tid < 128)  pSqs[(size_t)(tid - 64) * NBLK + bid] = stats[1][tid - 64];
}

// ---------------------------------------------------------------------------
// K2: reduce partials -> per-channel scale/shift
// ---------------------------------------------------------------------------
__global__ __launch_bounds__(256) void k2_stats(
    const float* __restrict__ pSum, const float* __restrict__ pSqs,
    const float* __restrict__ gamma, const float* __restrict__ beta,
    float* __restrict__ ss) {
  const int o = blockIdx.x;
  const int tid = threadIdx.x;
  double s = 0.0, q = 0.0;
  for (int i = tid; i < NBLK; i += 256) {
    s += (double)pSum[(size_t)o * NBLK + i];
    q += (double)pSqs[(size_t)o * NBLK + i];
  }
  __shared__ double sd[256], qd[256];
  sd[tid] = s; qd[tid] = q;
  __syncthreads();
  for (int step = 128; step > 0; step >>= 1) {
    if (tid < step) { sd[tid] += sd[tid + step]; qd[tid] += qd[tid + step]; }
    __syncthreads();
  }
  if (tid == 0) {
    const double cnt = 480000.0;
    double mean = sd[0] / cnt;
    double var = qd[0] / cnt - mean * mean;
    float inv = rsqrtf((float)var + EPS_);
    float sc = gamma[o] * inv;
    float sh = beta[o] - (float)mean * sc;
    ss[2 * o] = sc;
    ss[2 * o + 1] = sh;
  }
}

// ---------------------------------------------------------------------------
// K3: out = relu(scale[c]*y + shift[c] + x), in place on d_out (y staged there)
// ---------------------------------------------------------------------------
__global__ __launch_bounds__(256) void k3_finish(
    const float* __restrict__ x, const float* __restrict__ ss,
    float* __restrict__ y) {
  __shared__ float s_ss[128];
  if (threadIdx.x < 128) s_ss[threadIdx.x] = ss[threadIdx.x];
  __syncthreads();
  const long total = 7680000;   // float4 count; 1875 float4 per (n,c)-plane
  for (long i = (long)blockIdx.x * 256 + threadIdx.x; i < total; i += (long)gridDim.x * 256) {
    int plane = (int)(i / 1875);
    int c = plane & 63;
    float sc = s_ss[2 * c], sh = s_ss[2 * c + 1];
    float4 yv = reinterpret_cast<float4*>(y)[i];
    float4 xv = reinterpret_cast<const float4*>(x)[i];
    float4 o;
    o.x = fmaxf(sc * yv.x + sh + xv.x, 0.f);
    o.y = fmaxf(sc * yv.y + sh + xv.y, 0.f);
    o.z = fmaxf(sc * yv.z + sh + xv.z, 0.f);
    o.w = fmaxf(sc * yv.w + sh + xv.w, 0.f);
    reinterpret_cast<float4*>(y)[i] = o;
  }
}

extern "C" void kernel_launch(void* const* d_in, const int* in_sizes, int n_in,
                              void* d_out, int out_size, void* d_ws, size_t ws_size,
                              hipStream_t stream) {
  const float* x     = (const float*)d_in[0];
  const float* A     = (const float*)d_in[1];
  const float* W     = (const float*)d_in[2];
  const float* b     = (const float*)d_in[3];
  const float* gamma = (const float*)d_in[4];
  const float* beta  = (const float*)d_in[5];
  float* y = (float*)d_out;                  // stage y in d_out, finish in place

  float* pSum = (float*)d_ws;                // 64*4800 floats
  float* pSqs = pSum + 64 * NBLK;            // 64*4800 floats
  float* ss   = pSqs + 64 * NBLK;            // 128 floats

  k1_compute<<<NBLK, 256, 0, stream>>>(x, A, W, b, y, pSum, pSqs);
  k2_stats<<<64, 256, 0, stream>>>(pSum, pSqs, gamma, beta, ss);
  k3_finish<<<2048, 256, 0, stream>>>(x, ss, y);
}

// Round 2
// 181.568 us; speedup vs baseline: 1.2570x; 1.2570x over previous
//
#include <hip/hip_runtime.h>
#include <hip/hip_bf16.h>

// Problem constants
#define N_ 64
#define C_ 64
#define T_ 300
#define V_ 25
#define K_ 3
#define TB 4              // t-values per block
#define XP 136            // xs pitch (elements): [c][tt*32+v], 272B rows -> bank stride 4 (uniform)
#define ZP 200            // zT pitch (elements): [col][kc], 400B rows -> bank stride 4 (uniform)
#define NBLK 4800         // N_ * T_/TB
#define EPS_ 1e-5f

typedef __bf16 bf16_t;
typedef __bf16 bf16x4 __attribute__((ext_vector_type(4)));
typedef __bf16 bf16x8 __attribute__((ext_vector_type(8)));
typedef float f32x4 __attribute__((ext_vector_type(4)));

static __device__ __forceinline__ bf16_t tobf(float f) { return (bf16_t)f; }

// ---------------------------------------------------------------------------
// K1: y[n,o,t,w] = sum_k sum_c W[k,o,c] * (sum_v x[n,c,t,v] A[k,v,w]) + bsum[o]
// One block = (n, 4 t-values), processed as two tt-pair halves to keep zT small.
// Stage A per (tt, cf=wv): D[c16][w16] -> lane holds 4 consecutive c => b64 zT writes.
// Stage B: Y[o][col] over kc=192, cols = ttl*32+w (pads are true zeros via afrag).
// ---------------------------------------------------------------------------
__global__ __launch_bounds__(256, 3) void k1_compute(
    const float* __restrict__ x, const float* __restrict__ A,
    const float* __restrict__ W, const float* __restrict__ b,
    float* __restrict__ y, float* __restrict__ pSum, float* __restrict__ pSqs) {
  // LDS: xs 17.0KB + zT 25.0KB + stats 0.5KB = 42.5KB -> 3 blocks/CU
  __shared__ __align__(16) bf16_t xs[64 * XP];   // [c][tt*32+v]
  __shared__ __align__(16) bf16_t zT[64 * ZP];   // [col = ttl*32+w][kc]
  __shared__ float stats[2][64];

  const int bid = blockIdx.x;
  const int n = bid / (T_ / TB);
  const int t0 = (bid % (T_ / TB)) * TB;
  const int tid = threadIdx.x;
  const int lane = tid & 63;
  const int wv = tid >> 6;        // wave 0..3
  const int l15 = lane & 15;
  const int lg = lane >> 4;       // 0..3

  // --- W fragments (stage-B A-operand). Wave wv owns output rows o = wv*16..+15.
  // k-slot convention (all frags): k-slot = lg*8 + j
  bf16x8 wfrag[6];
  {
    const int o = wv * 16 + l15;
    #pragma unroll
    for (int kf = 0; kf < 6; ++kf) {
      int kc0 = kf * 32 + lg * 8;           // kc = k*64 + c
      int k = kc0 >> 6, c = kc0 & 63;       // 8 consecutive c, same k
      const float* wp = W + ((k * 64 + o) * 64 + c);
      bf16x8 f;
      #pragma unroll
      for (int j = 0; j < 8; ++j) f[j] = tobf(wp[j]);
      wfrag[kf] = f;
    }
  }
  // --- A-matrix fragments (stage-A B-operand): Ak[v][w], v pad 25->32, w pad 25->32 (zeros)
  bf16x8 afrag[3][2];
  #pragma unroll
  for (int k = 0; k < 3; ++k)
    #pragma unroll
    for (int nf = 0; nf < 2; ++nf) {
      int w = nf * 16 + l15;
      bf16x8 f;
      #pragma unroll
      for (int j = 0; j < 8; ++j) {
        int v = lg * 8 + j;
        float val = (v < V_ && w < V_) ? A[(k * V_ + v) * V_ + w] : 0.f;
        f[j] = tobf(val);
      }
      afrag[k][nf] = f;
    }

  // --- zero xs v-pads (v=25..31 per tt) so MFMA never reads NaN-ish garbage
  {
    int c = tid >> 2, tt = tid & 3;
    bf16_t* p = xs + c * XP + tt * 32;
    #pragma unroll
    for (int v = 25; v < 32; ++v) p[v] = tobf(0.f);
  }
  // --- load x tile -> xs (bf16). Per c: 100 contiguous floats (4 t-rows), 16B aligned.
  {
    const float* xb = x + (size_t)n * 480000 + t0 * 25;
    for (int f4 = tid; f4 < 1600; f4 += 256) {
      int c = f4 / 25, q = f4 - c * 25;
      const float4 val = *reinterpret_cast<const float4*>(xb + c * 7500 + 4 * q);
      const float* vp = reinterpret_cast<const float*>(&val);
      #pragma unroll
      for (int i = 0; i < 4; ++i) {
        int e = 4 * q + i;                  // 0..99
        int tt = e / 25, v = e - tt * 25;
        xs[c * XP + tt * 32 + v] = tobf(vp[i]);
      }
    }
  }
  __syncthreads();

  const int obase = wv * 16 + lg * 4;      // lane's 4 output rows: obase+r
  float bs[4];
  #pragma unroll
  for (int r = 0; r < 4; ++r)
    bs[r] = b[obase + r] + b[64 + obase + r] + b[128 + obase + r];

  float lsum[4] = {0.f,0.f,0.f,0.f}, lsq[4] = {0.f,0.f,0.f,0.f};
  float* yb = y + (size_t)n * 480000 + t0 * 25;

  #pragma unroll
  for (int h = 0; h < 2; ++h) {
    // --- stage A: z[kc][col] for cols = ttl*32+w. Wave wv handles cf = wv.
    #pragma unroll
    for (int ttl = 0; ttl < 2; ++ttl) {
      int tt = h * 2 + ttl;
      bf16x8 xf = *reinterpret_cast<const bf16x8*>(xs + (wv * 16 + l15) * XP + tt * 32 + lg * 8);
      #pragma unroll
      for (int k = 0; k < 3; ++k)
        #pragma unroll
        for (int nf = 0; nf < 2; ++nf) {
          f32x4 zero = {0.f, 0.f, 0.f, 0.f};
          f32x4 d = __builtin_amdgcn_mfma_f32_16x16x32_bf16(xf, afrag[k][nf], zero, 0, 0, 0);
          // D: row = lg*4+r -> c = wv*16+lg*4+r (4 consecutive kc), col = nf*16+l15 (w)
          int col = ttl * 32 + nf * 16 + l15;
          int kcb = k * 64 + wv * 16 + lg * 4;
          bf16x4 pk;
          #pragma unroll
          for (int r = 0; r < 4; ++r) pk[r] = tobf(d[r]);
          *reinterpret_cast<bf16x4*>(zT + col * ZP + kcb) = pk;   // 8B write, conflict-free
        }
    }
    __syncthreads();

    // --- stage B: Y[o][col] = sum_kc Wcat[o][kc] * z[kc][col]
    f32x4 acc[4];
    #pragma unroll
    for (int nf = 0; nf < 4; ++nf) { f32x4 z0 = {0.f,0.f,0.f,0.f}; acc[nf] = z0; }
    #pragma unroll
    for (int kf = 0; kf < 6; ++kf) {
      #pragma unroll
      for (int nf = 0; nf < 4; ++nf) {
        bf16x8 zf = *reinterpret_cast<const bf16x8*>(zT + (nf * 16 + l15) * ZP + kf * 32 + lg * 8);
        acc[nf] = __builtin_amdgcn_mfma_f32_16x16x32_bf16(wfrag[kf], zf, acc[nf], 0, 0, 0);
      }
    }

    // --- epilogue: bias, stats, store y (real cols only: w<25)
    #pragma unroll
    for (int nf = 0; nf < 4; ++nf) {
      int colidx = nf * 16 + l15;
      int ttl = colidx >> 5, w = colidx & 31;
      if (w < V_) {
        int t = h * 2 + ttl;                 // local t within block
        #pragma unroll
        for (int r = 0; r < 4; ++r) {
          float val = acc[nf][r] + bs[r];
          lsum[r] += val;
          lsq[r] += val * val;
          yb[(obase + r) * 7500 + t * 25 + w] = val;
        }
      }
    }
    if (h == 0) __syncthreads();   // protect zT before half-1 stage A
  }

  // reduce across the 16 lanes (l15) that share the same 4 rows
  #pragma unroll
  for (int d = 1; d < 16; d <<= 1) {
    #pragma unroll
    for (int r = 0; r < 4; ++r) {
      lsum[r] += __shfl_xor(lsum[r], d);
      lsq[r]  += __shfl_xor(lsq[r], d);
    }
  }
  if (l15 == 0) {
    #pragma unroll
    for (int r = 0; r < 4; ++r) {
      stats[0][obase + r] = lsum[r];
      stats[1][obase + r] = lsq[r];
    }
  }
  __syncthreads();
  if (tid < 64)        pSum[(size_t)tid * NBLK + bid] = stats[0][tid];
  else if (tid < 128)  pSqs[(size_t)(tid - 64) * NBLK + bid] = stats[1][tid - 64];
}

// ---------------------------------------------------------------------------
// K2: reduce partials -> per-channel scale/shift
// ---------------------------------------------------------------------------
__global__ __launch_bounds__(256) void k2_stats(
    const float* __restrict__ pSum, const float* __restrict__ pSqs,
    const float* __restrict__ gamma, const float* __restrict__ beta,
    float* __restrict__ ss) {
  const int o = blockIdx.x;
  const int tid = threadIdx.x;
  double s = 0.0, q = 0.0;
  for (int i = tid; i < NBLK; i += 256) {
    s += (double)pSum[(size_t)o * NBLK + i];
    q += (double)pSqs[(size_t)o * NBLK + i];
  }
  __shared__ double sd[256], qd[256];
  sd[tid] = s; qd[tid] = q;
  __syncthreads();
  for (int step = 128; step > 0; step >>= 1) {
    if (tid < step) { sd[tid] += sd[tid + step]; qd[tid] += qd[tid + step]; }
    __syncthreads();
  }
  if (tid == 0) {
    const double cnt = 480000.0;
    double mean = sd[0] / cnt;
    double var = qd[0] / cnt - mean * mean;
    float inv = rsqrtf((float)var + EPS_);
    float sc = gamma[o] * inv;
    float sh = beta[o] - (float)mean * sc;
    ss[2 * o] = sc;
    ss[2 * o + 1] = sh;
  }
}

// ---------------------------------------------------------------------------
// K3: out = relu(scale[c]*y + shift[c] + x), in place on d_out (y staged there)
// ---------------------------------------------------------------------------
__global__ __launch_bounds__(256) void k3_finish(
    const float* __restrict__ x, const float* __restrict__ ss,
    float* __restrict__ y) {
  __shared__ float s_ss[128];
  if (threadIdx.x < 128) s_ss[threadIdx.x] = ss[threadIdx.x];
  __syncthreads();
  const long total = 7680000;   // float4 count; 1875 float4 per (n,c)-plane
  for (long i = (long)blockIdx.x * 256 + threadIdx.x; i < total; i += (long)gridDim.x * 256) {
    int plane = (int)(i / 1875);
    int c = plane & 63;
    float sc = s_ss[2 * c], sh = s_ss[2 * c + 1];
    float4 yv = reinterpret_cast<float4*>(y)[i];
    float4 xv = reinterpret_cast<const float4*>(x)[i];
    float4 o;
    o.x = fmaxf(sc * yv.x + sh + xv.x, 0.f);
    o.y = fmaxf(sc * yv.y + sh + xv.y, 0.f);
    o.z = fmaxf(sc * yv.z + sh + xv.z, 0.f);
    o.w = fmaxf(sc * yv.w + sh + xv.w, 0.f);
    reinterpret_cast<float4*>(y)[i] = o;
  }
}

extern "C" void kernel_launch(void* const* d_in, const int* in_sizes, int n_in,
                              void* d_out, int out_size, void* d_ws, size_t ws_size,
                              hipStream_t stream) {
  const float* x     = (const float*)d_in[0];
  const float* A     = (const float*)d_in[1];
  const float* W     = (const float*)d_in[2];
  const float* b     = (const float*)d_in[3];
  const float* gamma = (const float*)d_in[4];
  const float* beta  = (const float*)d_in[5];
  float* y = (float*)d_out;                  // stage y in d_out, finish in place

  float* pSum = (float*)d_ws;                // 64*4800 floats
  float* pSqs = pSum + 64 * NBLK;            // 64*4800 floats
  float* ss   = pSqs + 64 * NBLK;            // 128 floats

  k1_compute<<<NBLK, 256, 0, stream>>>(x, A, W, b, y, pSum, pSqs);
  k2_stats<<<64, 256, 0, stream>>>(pSum, pSqs, gamma, beta, ss);
  k3_finish<<<2048, 256, 0, stream>>>(x, ss, y);
}

// Round 3
// 179.138 us; speedup vs baseline: 1.2740x; 1.0136x over previous
//
#include <hip/hip_runtime.h>
#include <hip/hip_bf16.h>

// Problem constants
#define N_ 64
#define C_ 64
#define T_ 300
#define V_ 25
#define K_ 3
#define TT 12             // t-values per block
#define NTILE 25          // T_/TT
#define NBLK 1600         // N_ * NTILE
#define EPS_ 1e-5f

typedef __bf16 bf16_t;
typedef __bf16 bf16x8 __attribute__((ext_vector_type(8)));
typedef float f32x4 __attribute__((ext_vector_type(4)));
typedef float f32x4u __attribute__((ext_vector_type(4), aligned(4)));  // dword-aligned vec load

static __device__ __forceinline__ bf16_t tobf(float f) { return (bf16_t)f; }

// Load one stage-A A-operand fragment: 8 bf16 = x[c][t][v = lg*8 .. lg*8+7].
// lg<3: v<=23 always real/in-bounds (2 dword-aligned dwordx4 loads).
// lg=3: only v=24 is real; v=25..31 are zero (matching zeroed A rows).
static __device__ __forceinline__ bf16x8 load_xfrag(const float* p, int lg) {
  bf16x8 f;
  if (lg < 3) {
    f32x4u a = *reinterpret_cast<const f32x4u*>(p);
    f32x4u b = *reinterpret_cast<const f32x4u*>(p + 4);
    f[0] = tobf(a[0]); f[1] = tobf(a[1]); f[2] = tobf(a[2]); f[3] = tobf(a[3]);
    f[4] = tobf(b[0]); f[5] = tobf(b[1]); f[6] = tobf(b[2]); f[7] = tobf(b[3]);
  } else {
    f[0] = tobf(p[0]);
    f[1] = tobf(0.f); f[2] = tobf(0.f); f[3] = tobf(0.f);
    f[4] = tobf(0.f); f[5] = tobf(0.f); f[6] = tobf(0.f); f[7] = tobf(0.f);
  }
  return f;
}

// ---------------------------------------------------------------------------
// K1: y[n,o,t,w] = sum_k sum_c W[k,o,c] * (sum_v x[n,c,t,v] A[k,v,w]) + bsum[o]
// Register-chained: stage-A D feeds stage-B B-operand directly (no LDS, no
// shuffles) via a permuted per-lane c-row map. One barrier per block (stats).
// Block = (n, 12 t's); wave wv owns output rows o = wv*16..wv*16+15.
// ---------------------------------------------------------------------------
__global__ __launch_bounds__(256, 4) void k1_compute(
    const float* __restrict__ x, const float* __restrict__ A,
    const float* __restrict__ W, const float* __restrict__ b,
    float* __restrict__ y, float* __restrict__ pSum, float* __restrict__ pSqs) {
  __shared__ float stats[2][64];

  const int bid = blockIdx.x;
  const int n = bid / NTILE;
  const int t0 = (bid - n * NTILE) * TT;
  const int tid = threadIdx.x;
  const int lane = tid & 63;
  const int wv = tid >> 6;        // wave 0..3 -> o-block
  const int l15 = lane & 15;
  const int lg = lane >> 4;       // 0..3

  // --- W fragments (stage-B A-operand, 16x16x32): row=l15 -> o, k-slot lg*8+j -> kc.
  // chunk ch = k*2 + chalf covers kc = k*64 + chalf*32 + (lg*8+j).
  bf16x8 wfrag[6];
  {
    const int o = wv * 16 + l15;
    #pragma unroll
    for (int k = 0; k < 3; ++k)
      #pragma unroll
      for (int ch = 0; ch < 2; ++ch) {
        const float* wp = W + ((k * 64 + o) * 64 + ch * 32 + lg * 8);
        f32x4u a = *reinterpret_cast<const f32x4u*>(wp);
        f32x4u c4 = *reinterpret_cast<const f32x4u*>(wp + 4);
        bf16x8 f;
        f[0] = tobf(a[0]); f[1] = tobf(a[1]); f[2] = tobf(a[2]); f[3] = tobf(a[3]);
        f[4] = tobf(c4[0]); f[5] = tobf(c4[1]); f[6] = tobf(c4[2]); f[7] = tobf(c4[3]);
        wfrag[k * 2 + ch] = f;
      }
  }
  // --- A-matrix fragments (stage-A B-operand): Ak[v][w], v pad 25->32, w pad 25->32 (zeros)
  bf16x8 afrag[3][2];
  #pragma unroll
  for (int k = 0; k < 3; ++k)
    #pragma unroll
    for (int wh = 0; wh < 2; ++wh) {
      int w = wh * 16 + l15;
      bf16x8 f;
      #pragma unroll
      for (int j = 0; j < 8; ++j) {
        int v = lg * 8 + j;
        float val = (v < V_ && w < V_) ? A[(k * V_ + v) * V_ + w] : 0.f;
        f[j] = tobf(val);
      }
      afrag[k][wh] = f;
    }

  // --- per-lane x row pointers. Permuted row map so stage-A D rows == stage-B kc slots:
  // frag (chalf, sub): c = chalf*32 + 8*(l15>>2) + 4*sub + (l15&3)
  const int crow = 8 * (l15 >> 2) + (l15 & 3);
  const float* xb = x + (size_t)n * 480000 + (size_t)t0 * 25 + lg * 8;
  const float* xrow[4];
  #pragma unroll
  for (int q = 0; q < 4; ++q) {   // q = chalf*2 + sub
    int c = ((q >> 1) * 32) + ((q & 1) * 4) + crow;
    xrow[q] = xb + (size_t)c * 7500;
  }

  const int obase = wv * 16 + lg * 4;      // lane's 4 output rows: obase+r
  float bs[4];
  #pragma unroll
  for (int r = 0; r < 4; ++r)
    bs[r] = b[obase + r] + b[64 + obase + r] + b[128 + obase + r];

  float lsum[4] = {0.f,0.f,0.f,0.f}, lsq[4] = {0.f,0.f,0.f,0.f};
  float* yb = y + (size_t)n * 480000 + (size_t)t0 * 25;
  const int w_lo = l15;            // wh=0 col
  const int w_hi = 16 + l15;       // wh=1 col (valid if <25)

  for (int t = 0; t < TT; ++t) {
    bf16x8 xf[4];
    #pragma unroll
    for (int q = 0; q < 4; ++q) xf[q] = load_xfrag(xrow[q] + t * 25, lg);

    #pragma unroll
    for (int wh = 0; wh < 2; ++wh) {
      f32x4 acc0 = {0.f,0.f,0.f,0.f}, acc1 = {0.f,0.f,0.f,0.f};
      #pragma unroll
      for (int k = 0; k < 3; ++k) {
        #pragma unroll
        for (int ch = 0; ch < 2; ++ch) {
          f32x4 zero = {0.f,0.f,0.f,0.f};
          f32x4 dP = __builtin_amdgcn_mfma_f32_16x16x32_bf16(xf[ch*2+0], afrag[k][wh], zero, 0, 0, 0);
          f32x4 dQ = __builtin_amdgcn_mfma_f32_16x16x32_bf16(xf[ch*2+1], afrag[k][wh], zero, 0, 0, 0);
          bf16x8 zf;
          zf[0] = tobf(dP[0]); zf[1] = tobf(dP[1]); zf[2] = tobf(dP[2]); zf[3] = tobf(dP[3]);
          zf[4] = tobf(dQ[0]); zf[5] = tobf(dQ[1]); zf[6] = tobf(dQ[2]); zf[7] = tobf(dQ[3]);
          if (ch == 0)
            acc0 = __builtin_amdgcn_mfma_f32_16x16x32_bf16(wfrag[k*2+ch], zf, acc0, 0, 0, 0);
          else
            acc1 = __builtin_amdgcn_mfma_f32_16x16x32_bf16(wfrag[k*2+ch], zf, acc1, 0, 0, 0);
        }
      }
      // epilogue: bias, stats, store y (cols w = wh*16+l15 < 25)
      const int w = wh ? w_hi : w_lo;
      if (w < V_) {
        #pragma unroll
        for (int r = 0; r < 4; ++r) {
          float val = acc0[r] + acc1[r] + bs[r];
          lsum[r] += val;
          lsq[r] += val * val;
          yb[(size_t)(obase + r) * 7500 + t * 25 + w] = val;
        }
      }
    }
  }

  // reduce across the 16 lanes (l15) that share the same 4 o-rows
  #pragma unroll
  for (int d = 1; d < 16; d <<= 1) {
    #pragma unroll
    for (int r = 0; r < 4; ++r) {
      lsum[r] += __shfl_xor(lsum[r], d);
      lsq[r]  += __shfl_xor(lsq[r], d);
    }
  }
  if (l15 == 0) {
    #pragma unroll
    for (int r = 0; r < 4; ++r) {
      stats[0][obase + r] = lsum[r];
      stats[1][obase + r] = lsq[r];
    }
  }
  __syncthreads();
  if (tid < 64)        pSum[(size_t)tid * NBLK + bid] = stats[0][tid];
  else if (tid < 128)  pSqs[(size_t)(tid - 64) * NBLK + bid] = stats[1][tid - 64];
}

// ---------------------------------------------------------------------------
// K2: reduce partials -> per-channel scale/shift
// ---------------------------------------------------------------------------
__global__ __launch_bounds__(256) void k2_stats(
    const float* __restrict__ pSum, const float* __restrict__ pSqs,
    const float* __restrict__ gamma, const float* __restrict__ beta,
    float* __restrict__ ss) {
  const int o = blockIdx.x;
  const int tid = threadIdx.x;
  double s = 0.0, q = 0.0;
  for (int i = tid; i < NBLK; i += 256) {
    s += (double)pSum[(size_t)o * NBLK + i];
    q += (double)pSqs[(size_t)o * NBLK + i];
  }
  __shared__ double sd[256], qd[256];
  sd[tid] = s; qd[tid] = q;
  __syncthreads();
  for (int step = 128; step > 0; step >>= 1) {
    if (tid < step) { sd[tid] += sd[tid + step]; qd[tid] += qd[tid + step]; }
    __syncthreads();
  }
  if (tid == 0) {
    const double cnt = 480000.0;
    double mean = sd[0] / cnt;
    double var = qd[0] / cnt - mean * mean;
    float inv = rsqrtf((float)var + EPS_);
    float sc = gamma[o] * inv;
    float sh = beta[o] - (float)mean * sc;
    ss[2 * o] = sc;
    ss[2 * o + 1] = sh;
  }
}

// ---------------------------------------------------------------------------
// K3: out = relu(scale[c]*y + shift[c] + x), in place on d_out (y staged there).
// One block per (n,c) plane: 7500 floats = 1875 float4, uniform scale/shift.
// ---------------------------------------------------------------------------
__global__ __launch_bounds__(256) void k3_finish(
    const float* __restrict__ x, const float* __restrict__ ss,
    float* __restrict__ y) {
  const int p = blockIdx.x;       // 0..4095 = n*64 + c
  const int c = p & 63;
  const float sc = ss[2 * c];
  const float sh = ss[2 * c + 1];
  const float4* xv = reinterpret_cast<const float4*>(x + (size_t)p * 7500);
  float4* yv = reinterpret_cast<float4*>(y + (size_t)p * 7500);
  for (int i = threadIdx.x; i < 1875; i += 256) {
    float4 a = yv[i];
    float4 b4 = xv[i];
    float4 o;
    o.x = fmaxf(sc * a.x + sh + b4.x, 0.f);
    o.y = fmaxf(sc * a.y + sh + b4.y, 0.f);
    o.z = fmaxf(sc * a.z + sh + b4.z, 0.f);
    o.w = fmaxf(sc * a.w + sh + b4.w, 0.f);
    yv[i] = o;
  }
}

extern "C" void kernel_launch(void* const* d_in, const int* in_sizes, int n_in,
                              void* d_out, int out_size, void* d_ws, size_t ws_size,
                              hipStream_t stream) {
  const float* x     = (const float*)d_in[0];
  const float* A     = (const float*)d_in[1];
  const float* W     = (const float*)d_in[2];
  const float* b     = (const float*)d_in[3];
  const float* gamma = (const float*)d_in[4];
  const float* beta  = (const float*)d_in[5];
  float* y = (float*)d_out;                  // stage y in d_out, finish in place

  float* pSum = (float*)d_ws;                // 64*NBLK floats
  float* pSqs = pSum + 64 * NBLK;            // 64*NBLK floats
  float* ss   = pSqs + 64 * NBLK;            // 128 floats

  k1_compute<<<NBLK, 256, 0, stream>>>(x, A, W, b, y, pSum, pSqs);
  k2_stats<<<64, 256, 0, stream>>>(pSum, pSqs, gamma, beta, ss);
  k3_finish<<<4096, 256, 0, stream>>>(x, ss, y);
}